// Round 18
// baseline (264.394 us; speedup 1.0000x reference)
//
#include <hip/hip_runtime.h>
#include <math.h>

using bf16x8 = __attribute__((ext_vector_type(8))) short;
using f32x4  = __attribute__((ext_vector_type(4))) float;

#define GCN_CAP 1536   // max staged CSR entries per 16-node block (avg ~208)

__device__ __forceinline__ unsigned short f2b(float f) {
  unsigned u = __float_as_uint(f);
  u += 0x7FFFu + ((u >> 16) & 1u);
  return (unsigned short)(u >> 16);
}
__device__ __forceinline__ float b2f(unsigned short h) {
  return __uint_as_float((unsigned)h << 16);
}
__device__ __forceinline__ float2 upk(unsigned u) {
  return make_float2(__uint_as_float(u << 16), __uint_as_float(u & 0xFFFF0000u));
}

// Fragment-packed weight layout: Wp[colblk][ks][lane][8]; B-fragment load for
// (colblk, ks) is lane -> Wp[((colblk*4+ks)*64 + lane)*8 .. +8]: one contiguous
// 1KB wave-load. lane=(hi*16+lo) holds W[k=ks*32+hi*8..+8][col=colblk*16+lo].
__device__ __forceinline__ long pk_off(int c, int r) {   // c = out col, r = k
  return ((long)((c >> 4) * 4 + (r >> 5)) << 9)
       + (long)(((((r >> 3) & 3) << 4) + (c & 15)) * 8 + (r & 7));
}

// ---------------- graph prep ----------------

__global__ void k_degree(const int* __restrict__ dst, int* __restrict__ degi, int E) {
  int e = blockIdx.x * blockDim.x + threadIdx.x;
  if (e < E) atomicAdd(&degi[dst[e]], 1);
}

// per-256 block sums of deg (also emits dinv — folds former k_dinv launch)
__global__ __launch_bounds__(256)
void k_part(const int* __restrict__ deg, int* __restrict__ part,
            float* __restrict__ dinv, int n) {
  __shared__ int l[256];
  int tid = threadIdx.x, i = blockIdx.x * 256 + tid;
  int v = (i < n) ? deg[i] : 0;
  if (i < n) dinv[i] = rsqrtf((float)(v + 1));  // +1 self-loop
  l[tid] = v;
  __syncthreads();
  for (int s = 128; s; s >>= 1) { if (tid < s) l[tid] += l[tid + s]; __syncthreads(); }
  if (!tid) part[blockIdx.x] = l[0];
}

__global__ __launch_bounds__(1024)
void k_scanpart(int* __restrict__ part, int np, int* __restrict__ off_n) {
  __shared__ int l[1024];
  int tid = threadIdx.x;
  int v = (tid < np) ? part[tid] : 0;
  l[tid] = v;
  __syncthreads();
  for (int s = 1; s < 1024; s <<= 1) {
    int t = (tid >= s) ? l[tid - s] : 0;
    __syncthreads();
    l[tid] += t;
    __syncthreads();
  }
  if (tid < np) part[tid] = l[tid] - v;   // exclusive
  if (tid == np - 1) *off_n = l[tid];     // total = E
}

// exclusive scan within block + partial base; also zero-inits cursor
__global__ __launch_bounds__(256)
void k_off(const int* __restrict__ deg, const int* __restrict__ part,
           int* __restrict__ off, int* __restrict__ cursor, int n) {
  __shared__ int l[256];
  int tid = threadIdx.x, i = blockIdx.x * 256 + tid;
  int v = (i < n) ? deg[i] : 0;
  l[tid] = v;
  __syncthreads();
  for (int s = 1; s < 256; s <<= 1) {
    int t = (tid >= s) ? l[tid - s] : 0;
    __syncthreads();
    l[tid] += t;
    __syncthreads();
  }
  if (i < n) {
    off[i] = part[blockIdx.x] + l[tid] - v;
    cursor[i] = 0;
  }
}

__global__ void k_scatter(const int* __restrict__ srcv, const int* __restrict__ dstv,
                          const float* __restrict__ dinv, const int* __restrict__ off,
                          int* __restrict__ cursor, int* __restrict__ csr_src,
                          float* __restrict__ csr_norm, int E) {
  int e = blockIdx.x * blockDim.x + threadIdx.x;
  if (e >= E) return;
  int d = dstv[e];
  int p = atomicAdd(&cursor[d], 1);
  int slot = off[d] + p;
  int s = srcv[e];
  csr_src[slot] = s;
  csr_norm[slot] = dinv[s] * dinv[d];
}

// ---------------- x (f32) -> bf16 ----------------

__global__ void k_cvtx(const float* __restrict__ x, unsigned short* __restrict__ xb,
                       long n4) {
  long t = (long)blockIdx.x * blockDim.x + threadIdx.x;
  if (t >= n4) return;
  float4 v = ((const float4*)x)[t];
  unsigned lo = (unsigned)f2b(v.x) | ((unsigned)f2b(v.y) << 16);
  unsigned hi = (unsigned)f2b(v.z) | ((unsigned)f2b(v.w) << 16);
  ((uint2*)xb)[t] = make_uint2(lo, hi);
}

// ---------------- weight convert: fp32 [128,128] -> fragment-packed bf16 ----------

__global__ __launch_bounds__(256)
void k_cvtw(const float* gw0, const float* gw1, const float* gw2,
            const float* wk, const float* wv, const float* wq, const float* ow,
            unsigned short* gwT0, unsigned short* gwT1, unsigned short* gwT2,
            unsigned short* wkvT, unsigned short* wqT, unsigned short* owT) {
  const float* src; unsigned short* dst;
  switch (blockIdx.y) {
    case 0: src = gw0; dst = gwT0; break;
    case 1: src = gw1; dst = gwT1; break;
    case 2: src = gw2; dst = gwT2; break;
    case 3: src = wk;  dst = wkvT; break;
    case 4: src = wv;  dst = wkvT + 128 * 128; break;   // colblk 8..15
    case 5: src = wq;  dst = wqT; break;
    default: src = ow; dst = owT; break;
  }
  int t = blockIdx.x * 256 + threadIdx.x;   // grid.x = 64
  int r = t >> 7, c = t & 127;              // r = k (input dim), c = out col
  dst[pk_off(c, r)] = f2b(src[t]);
}

// ---------------- fused GCN layer (R13 anchor + block-local CSR staged in LDS) ------
// out = LN(relu((A_hat @ prev) @ W + b)) + prev, using (A_hat H) W == A_hat (H W).
// Block = 128 thr (2 waves) = 16 nodes. CSR is contiguous per block: the whole
// segment csr[off[n0]..off[n0+16]) (~208 entries) is staged to LDS once, so
// phase A's idx/norm reads cost ~120cy LDS instead of ~450cy L2 — removing the
// idx step from the per-node latency chain with ZERO cross-iteration registers
// (the R12/R14/R16 spill trap can't fire). Fallback to global reads if a
// block's segment exceeds GCN_CAP (correct for any input).

__global__ __launch_bounds__(128, 6)
void k_gcn_layer(const unsigned short* __restrict__ embp,  // [N][128] bf16
                 const int* __restrict__ off, const int* __restrict__ csr_src,
                 const float* __restrict__ csr_norm, const float* __restrict__ dinv,
                 const unsigned short* __restrict__ wT,    // fragment-packed
                 const float* __restrict__ bias,
                 const float* __restrict__ ln_g, const float* __restrict__ ln_b,
                 unsigned short* __restrict__ embo, int N) {
  __shared__ unsigned a_sw[16 * 64];      // 16 rows x 256B, 16B-chunk XOR swizzle
  __shared__ float lnsum[16][2], lnsq[16][2];
  __shared__ int   eidx[GCN_CAP];
  __shared__ float enrm[GCN_CAP];

  int tid = threadIdx.x, lane = tid & 63, w = tid >> 6;
  int g = lane >> 4, c16 = lane & 15;
  long n0 = (long)blockIdx.x * 16;

  // ---- stage this block's CSR segment into LDS (coalesced, once)
  long nend = (n0 + 16 < (long)N) ? n0 + 16 : (long)N;
  int e0 = off[n0];
  int e1 = off[nend];
  int cnt = e1 - e0; if (cnt > GCN_CAP) cnt = GCN_CAP;
  for (int i = tid; i < cnt; i += 128) {
    eidx[i] = csr_src[e0 + i];
    enrm[i] = csr_norm[e0 + i];
  }
  __syncthreads();

  // ---- phase A: aggregate 8 nodes for this wave (idx/norm from LDS)
#pragma unroll
  for (int t = 0; t < 8; ++t) {
    int row = w * 8 + t;
    long node = n0 + row;
    long nc = node < N ? node : N - 1;
    float dn = dinv[nc];
    int s0 = off[nc], s1 = off[nc + 1];
    bool inl = (s1 - e0) <= GCN_CAP;   // whole range staged?
    float acc[8];
    {
      uint4 rs_ = *(const uint4*)&embp[nc * 128 + c16 * 8];
      float wgt = (g == 0) ? dn * dn : 0.f;   // self loop counted once
      float2 f;
      f = upk(rs_.x); acc[0] = f.x * wgt; acc[1] = f.y * wgt;
      f = upk(rs_.y); acc[2] = f.x * wgt; acc[3] = f.y * wgt;
      f = upk(rs_.z); acc[4] = f.x * wgt; acc[5] = f.y * wgt;
      f = upk(rs_.w); acc[6] = f.x * wgt; acc[7] = f.y * wgt;
    }
    for (int i = s0; i < s1; i += 16) {
      int id[4]; float nm[4];
      if (inl) {
#pragma unroll
        for (int u = 0; u < 4; ++u) {
          int j = i + u * 4 + g;
          int jj = (j < s1 ? j : s1 - 1) - e0;
          id[u] = eidx[jj];
          nm[u] = j < s1 ? enrm[jj] : 0.f;
        }
      } else {
#pragma unroll
        for (int u = 0; u < 4; ++u) {
          int j = i + u * 4 + g;
          int jj = j < s1 ? j : s1 - 1;
          id[u] = csr_src[jj];
          nm[u] = j < s1 ? csr_norm[jj] : 0.f;
        }
      }
      uint4 rv[4];
#pragma unroll
      for (int u = 0; u < 4; ++u)
        rv[u] = *(const uint4*)&embp[(long)id[u] * 128 + c16 * 8];
#pragma unroll
      for (int u = 0; u < 4; ++u) {
        float2 f0 = upk(rv[u].x), f1 = upk(rv[u].y);
        float2 f2 = upk(rv[u].z), f3 = upk(rv[u].w);
        acc[0] += f0.x * nm[u]; acc[1] += f0.y * nm[u];
        acc[2] += f1.x * nm[u]; acc[3] += f1.y * nm[u];
        acc[4] += f2.x * nm[u]; acc[5] += f2.y * nm[u];
        acc[6] += f3.x * nm[u]; acc[7] += f3.y * nm[u];
      }
    }
    // combine the 4 row-groups (lanes differing in bits 4,5)
#pragma unroll
    for (int k = 0; k < 8; ++k) {
      acc[k] += __shfl_xor(acc[k], 16);
      acc[k] += __shfl_xor(acc[k], 32);
    }
    if (g == 0) {
      unsigned* dst = (unsigned*)((char*)a_sw +
                      (row * 256 + ((c16 * 16) ^ ((row & 7) << 4))));
      dst[0] = (unsigned)f2b(acc[0]) | ((unsigned)f2b(acc[1]) << 16);
      dst[1] = (unsigned)f2b(acc[2]) | ((unsigned)f2b(acc[3]) << 16);
      dst[2] = (unsigned)f2b(acc[4]) | ((unsigned)f2b(acc[5]) << 16);
      dst[3] = (unsigned)f2b(acc[6]) | ((unsigned)f2b(acc[7]) << 16);
    }
  }
  __syncthreads();

  // ---- phase B: [16,128] = A @ W ; this wave: cols w*64..+64 (packed B loads)
  int lo = lane & 15, hi = lane >> 4;
  f32x4 acc2[4] = {};
#pragma unroll
  for (int ks = 0; ks < 4; ++ks) {
    int k0 = ks * 32 + hi * 8;
    bf16x8 a = *(const bf16x8*)((char*)a_sw + lo * 256 + ((k0 * 2) ^ ((lo & 7) << 4)));
#pragma unroll
    for (int cf = 0; cf < 4; ++cf) {
      bf16x8 b = *(const bf16x8*)&wT[((((long)(w * 4 + cf)) * 4 + ks) * 64 + lane) * 8];
      acc2[cf] = __builtin_amdgcn_mfma_f32_16x16x32_bf16(a, b, acc2[cf], 0, 0, 0);
    }
  }

  // ---- phase C: bias + relu + LN + residual + store
  int cb0 = w * 64;
  float vreg[4][4];   // [cf][j] ; row = hi*4+j, col = cb0+cf*16+lo
#pragma unroll
  for (int j = 0; j < 4; ++j) {
    float s = 0.f, q = 0.f;
#pragma unroll
    for (int cf = 0; cf < 4; ++cf) {
      int col = cb0 + cf * 16 + lo;
      float v = fmaxf(acc2[cf][j] + bias[col], 0.f);
      vreg[cf][j] = v;
      s += v; q += v * v;
    }
#pragma unroll
    for (int m = 1; m < 16; m <<= 1) { s += __shfl_xor(s, m); q += __shfl_xor(q, m); }
    if (lo == 0) { lnsum[hi * 4 + j][w] = s; lnsq[hi * 4 + j][w] = q; }
  }
  __syncthreads();
#pragma unroll
  for (int j = 0; j < 4; ++j) {
    int row = hi * 4 + j;
    float sum = lnsum[row][0] + lnsum[row][1];
    float sq  = lnsq[row][0] + lnsq[row][1];
    float mu = sum * (1.f / 128.f);
    float var = sq * (1.f / 128.f) - mu * mu;
    float rs = rsqrtf(var + 1e-5f);
    long gr = n0 + row;
    if (gr < N) {
#pragma unroll
      for (int cf = 0; cf < 4; ++cf) {
        int col = cb0 + cf * 16 + lo;
        float z = (vreg[cf][j] - mu) * rs * ln_g[col] + ln_b[col]
                  + b2f(embp[gr * 128 + col]);
        embo[gr * 128 + col] = f2b(z);
      }
    }
  }
}

// ---------------- fused: kv-proj + q-proj + attention + LN + out-proj ----------------
// R11-proven structure: fragment-packed B weights (1KB coalesced wave-loads).
// Block = 256 thr (4 waves) handles 16 nodes. emb layout [3][N][128] bf16.

__global__ __launch_bounds__(256)
void k_attn_fused(const unsigned short* __restrict__ emb,   // [3][N][128]
                  const unsigned short* __restrict__ wkvT,  // packed, colblk 0-7=K, 8-15=V
                  const unsigned short* __restrict__ wqT,   // packed
                  const unsigned short* __restrict__ owT,   // packed
                  const float* __restrict__ ln_g, const float* __restrict__ ln_b,
                  const float* __restrict__ out_b,
                  unsigned short* __restrict__ zoutb, int N) {
  __shared__ unsigned short kvl[48 * 256];  // row = l*16+node : [K 0..127 | V 128..255]
  __shared__ unsigned short ql[16 * 128];
  __shared__ unsigned short zl[16 * 128];   // XOR-swizzled (byte ^= (row&7)<<4)

  int tid = threadIdx.x, lane = tid & 63, w = tid >> 6;
  int lo = lane & 15, hi = lane >> 4;
  long n0 = (long)blockIdx.x * 16;
  long nr = n0 + lo; if (nr >= N) nr = N - 1;

  // ---- phase 1: KV[48,256] = emb-tile @ Wkv ; this wave: cols w*64..+64
  {
    f32x4 acc[3][4] = {};
#pragma unroll
    for (int ks = 0; ks < 4; ++ks) {
      int k0 = ks * 32 + hi * 8;
      bf16x8 a[3];
#pragma unroll
      for (int l = 0; l < 3; ++l)
        a[l] = *(const bf16x8*)&emb[((long)l * N + nr) * 128 + k0];
#pragma unroll
      for (int cf = 0; cf < 4; ++cf) {
        bf16x8 b = *(const bf16x8*)&wkvT[((((long)(w * 4 + cf)) * 4 + ks) * 64 + lane) * 8];
#pragma unroll
        for (int l = 0; l < 3; ++l)
          acc[l][cf] = __builtin_amdgcn_mfma_f32_16x16x32_bf16(a[l], b, acc[l][cf], 0, 0, 0);
      }
    }
    int cb0 = w * 64;
#pragma unroll
    for (int l = 0; l < 3; ++l)
#pragma unroll
      for (int cf = 0; cf < 4; ++cf)
#pragma unroll
        for (int j = 0; j < 4; ++j)
          kvl[(l * 16 + hi * 4 + j) * 256 + cb0 + cf * 16 + lo] = f2b(acc[l][cf][j]);
  }

  // ---- phase 2: Q[16,128] = layer2-tile @ Wq ; this wave: cols w*32..+32
  {
    f32x4 aq[2] = {};
#pragma unroll
    for (int ks = 0; ks < 4; ++ks) {
      int k0 = ks * 32 + hi * 8;
      bf16x8 a = *(const bf16x8*)&emb[(2L * N + nr) * 128 + k0];
#pragma unroll
      for (int cf = 0; cf < 2; ++cf) {
        bf16x8 b = *(const bf16x8*)&wqT[((((long)(w * 2 + cf)) * 4 + ks) * 64 + lane) * 8];
        aq[cf] = __builtin_amdgcn_mfma_f32_16x16x32_bf16(a, b, aq[cf], 0, 0, 0);
      }
    }
    int cq0 = w * 32;
#pragma unroll
    for (int cf = 0; cf < 2; ++cf)
#pragma unroll
      for (int j = 0; j < 4; ++j)
        ql[(hi * 4 + j) * 128 + cq0 + cf * 16 + lo] = f2b(aq[cf][j]);
  }
  __syncthreads();

  // ---- phase 3: attention + LN ; wave handles nodes w*4 .. w*4+3
  {
    const unsigned* kvu = (const unsigned*)kvl;
    const unsigned* qu  = (const unsigned*)ql;
    int c = lane * 2;
    float gx = ln_g[c], gy = ln_g[c + 1], bx = ln_b[c], by = ln_b[c + 1];
#pragma unroll
    for (int it = 0; it < 4; ++it) {
      int node = w * 4 + it;
      float2 q = upk(qu[node * 64 + lane]);
      float s[3], vx[3], vy[3];
#pragma unroll
      for (int m = 0; m < 3; ++m) {
        int row = m * 16 + node;
        float2 k = upk(kvu[row * 128 + lane]);
        float2 v = upk(kvu[row * 128 + 64 + lane]);
        float p = q.x * k.x + q.y * k.y;
        p += __shfl_xor(p, 1); p += __shfl_xor(p, 2); p += __shfl_xor(p, 4);
        s[m] = p * 0.25f;   // /sqrt(16)
        vx[m] = v.x; vy[m] = v.y;
      }
      float mx = fmaxf(s[0], fmaxf(s[1], s[2]));
      float e0 = __expf(s[0] - mx), e1 = __expf(s[1] - mx), e2 = __expf(s[2] - mx);
      float inv = 1.f / (e0 + e1 + e2);
      float cx = (e0 * vx[0] + e1 * vx[1] + e2 * vx[2]) * inv;
      float cy = (e0 * vy[0] + e1 * vy[1] + e2 * vy[2]) * inv;
      float sum = cx + cy, sq = cx * cx + cy * cy;
#pragma unroll
      for (int m = 1; m < 64; m <<= 1) { sum += __shfl_xor(sum, m); sq += __shfl_xor(sq, m); }
      float mu = sum * (1.f / 128.f);
      float var = sq * (1.f / 128.f) - mu * mu;
      float rs = rsqrtf(var + 1e-5f);
      unsigned pk = (unsigned)f2b((cx - mu) * rs * gx + bx) |
                    ((unsigned)f2b((cy - mu) * rs * gy + by) << 16);
      *(unsigned*)((char*)zl + node * 256 + ((lane * 4) ^ ((node & 7) << 4))) = pk;
    }
  }
  __syncthreads();

  // ---- phase 4: zout[16,128] = z @ Wo + out_b (bf16 store) ; cols w*32..+32
  {
    int co0 = w * 32;
    f32x4 ao[2] = {};
#pragma unroll
    for (int ks = 0; ks < 4; ++ks) {
      int k0 = ks * 32 + hi * 8;
      bf16x8 a = *(const bf16x8*)((const char*)zl + lo * 256 + (((k0 * 2) ^ ((lo & 7) << 4))));
#pragma unroll
      for (int cf = 0; cf < 2; ++cf) {
        bf16x8 b = *(const bf16x8*)&owT[((((long)(w * 2 + cf)) * 4 + ks) * 64 + lane) * 8];
        ao[cf] = __builtin_amdgcn_mfma_f32_16x16x32_bf16(a, b, ao[cf], 0, 0, 0);
      }
    }
#pragma unroll
    for (int cf = 0; cf < 2; ++cf)
#pragma unroll
      for (int j = 0; j < 4; ++j) {
        long gn = n0 + hi * 4 + j;
        int col = co0 + cf * 16 + lo;
        if (gn < N) zoutb[gn * 128 + col] = f2b(ao[cf][j] + out_b[col]);
      }
  }
}

// ---------------- gather rows (bf16 zout -> f32 out); blockIdx.y = id set --------

__global__ void k_gather4(const unsigned short* __restrict__ zoutb,
                          const int* __restrict__ ids0, const int* __restrict__ ids1,
                          const int* __restrict__ ids2, const int* __restrict__ ids3,
                          float* __restrict__ outp, int rows) {
  int t = blockIdx.x * blockDim.x + threadIdx.x;  // one 16B bf16 chunk per thread
  if (t >= rows * 16) return;
  int s = blockIdx.y;
  const int* ids = (s == 0) ? ids0 : (s == 1) ? ids1 : (s == 2) ? ids2 : ids3;
  int row = t >> 4, c8 = t & 15;
  long id = ids[row];
  uint4 v = *(const uint4*)&zoutb[id * 128 + c8 * 8];
  float2 f0 = upk(v.x), f1 = upk(v.y), f2_ = upk(v.z), f3 = upk(v.w);
  float4* dst = (float4*)&outp[(((long)s * rows + row) * 128) + c8 * 8];
  dst[0] = make_float4(f0.x, f0.y, f1.x, f1.y);
  dst[1] = make_float4(f2_.x, f2_.y, f3.x, f3.y);
}

// ---------------- host ----------------

extern "C" void kernel_launch(void* const* d_in, const int* in_sizes, int n_in,
                              void* d_out, int out_size, void* d_ws, size_t ws_size,
                              hipStream_t stream) {
  const float* x = (const float*)d_in[0];
  const int* ei = (const int*)d_in[1];
  const int* ids[4] = {(const int*)d_in[2], (const int*)d_in[3],
                       (const int*)d_in[4], (const int*)d_in[5]};
  const float* gw[3] = {(const float*)d_in[7], (const float*)d_in[9], (const float*)d_in[11]};
  const float* gb[3] = {(const float*)d_in[8], (const float*)d_in[10], (const float*)d_in[12]};
  const float* wq = (const float*)d_in[13];
  const float* wk = (const float*)d_in[14];
  const float* wv = (const float*)d_in[15];
  const float* ln_g = (const float*)d_in[16];
  const float* ln_b = (const float*)d_in[17];
  const float* out_w = (const float*)d_in[18];
  const float* out_b = (const float*)d_in[19];

  const int N = in_sizes[0] / 128;
  const int E = in_sizes[1] / 2;
  const int P = in_sizes[2];

  char* w = (char*)d_ws;
  size_t o = 0;
  auto take = [&](size_t bytes) -> void* {
    void* p = w + o;
    o = (o + bytes + 255) & ~(size_t)255;
    return p;
  };
  int*   degi    = (int*)take((size_t)N * 4);
  int*   off     = (int*)take((size_t)(N + 1) * 4);
  int*   cursor  = (int*)take((size_t)N * 4);
  int*   part    = (int*)take(1024 * 4);
  float* dinv    = (float*)take((size_t)N * 4);
  int*   csr_src = (int*)take((size_t)E * 4);
  float* csr_nrm = (float*)take((size_t)E * 4);
  unsigned short* gwT0 = (unsigned short*)take(128 * 128 * 2);
  unsigned short* gwT1 = (unsigned short*)take(128 * 128 * 2);
  unsigned short* gwT2 = (unsigned short*)take(128 * 128 * 2);
  unsigned short* wkvT = (unsigned short*)take(256 * 128 * 2);
  unsigned short* wqT  = (unsigned short*)take(128 * 128 * 2);
  unsigned short* owT  = (unsigned short*)take(128 * 128 * 2);
  unsigned short* xbf  = (unsigned short*)take((size_t)N * 128 * 2);
  unsigned short* emball = (unsigned short*)take((size_t)3 * N * 128 * 2);
  unsigned short* zoutb = (unsigned short*)take((size_t)N * 128 * 2);
  (void)ws_size; (void)n_in; (void)out_size;

  hipMemsetAsync(degi, 0, (size_t)N * 4, stream);

  int eb = (E + 255) / 256;
  int nb = (N + 255) / 256;
  k_degree<<<eb, 256, 0, stream>>>(ei + E, degi, E);
  k_part<<<nb, 256, 0, stream>>>(degi, part, dinv, N);
  k_scanpart<<<1, 1024, 0, stream>>>(part, nb, off + N);
  k_off<<<nb, 256, 0, stream>>>(degi, part, off, cursor, N);
  k_scatter<<<eb, 256, 0, stream>>>(ei, ei + E, dinv, off, cursor, csr_src, csr_nrm, E);
  k_cvtw<<<dim3(64, 7), 256, 0, stream>>>(gw[0], gw[1], gw[2], wk, wv, wq, out_w,
                                          gwT0, gwT1, gwT2, wkvT, wqT, owT);
  long n4 = (long)N * 32;
  k_cvtx<<<(int)((n4 + 255) / 256), 256, 0, stream>>>(x, xbf, n4);

  unsigned short* gwT[3] = {gwT0, gwT1, gwT2};
  int lgrid = (N + 15) / 16;
  const unsigned short* prev = xbf;
  for (int l = 0; l < 3; ++l) {
    unsigned short* outp = emball + (size_t)l * N * 128;
    k_gcn_layer<<<lgrid, 128, 0, stream>>>(prev, off, csr_src, csr_nrm, dinv,
                                           gwT[l], gb[l], ln_g, ln_b, outp, N);
    prev = outp;
  }

  // fused kv/q projections + attention + LN + out-proj (packed weights, bf16 zout)
  k_attn_fused<<<(N + 15) / 16, 256, 0, stream>>>(emball, wkvT, wqT, owT,
                                                  ln_g, ln_b, out_b, zoutb, N);

  float* outf = (float*)d_out;
  int gb2 = (P * 16 + 255) / 256;
  k_gather4<<<dim3(gb2, 4), 256, 0, stream>>>(zoutb, ids[0], ids[1], ids[2], ids[3],
                                              outf, P);
}

// Round 19
// 248.349 us; speedup vs baseline: 1.0646x; 1.0646x over previous
//
#include <hip/hip_runtime.h>
#include <math.h>

using bf16x8 = __attribute__((ext_vector_type(8))) short;
using f32x4  = __attribute__((ext_vector_type(4))) float;

__device__ __forceinline__ unsigned short f2b(float f) {
  unsigned u = __float_as_uint(f);
  u += 0x7FFFu + ((u >> 16) & 1u);
  return (unsigned short)(u >> 16);
}
__device__ __forceinline__ float b2f(unsigned short h) {
  return __uint_as_float((unsigned)h << 16);
}
__device__ __forceinline__ float2 upk(unsigned u) {
  return make_float2(__uint_as_float(u << 16), __uint_as_float(u & 0xFFFF0000u));
}

// Fragment-packed weight layout: Wp[colblk][ks][lane][8]; B-fragment load for
// (colblk, ks) is lane -> Wp[((colblk*4+ks)*64 + lane)*8 .. +8]: one contiguous
// 1KB wave-load. lane=(hi*16+lo) holds W[k=ks*32+hi*8..+8][col=colblk*16+lo].
__device__ __forceinline__ long pk_off(int c, int r) {   // c = out col, r = k
  return ((long)((c >> 4) * 4 + (r >> 5)) << 9)
       + (long)(((((r >> 3) & 3) << 4) + (c & 15)) * 8 + (r & 7));
}

// ---------------- graph prep ----------------

__global__ void k_degree(const int* __restrict__ dst, int* __restrict__ degi, int E) {
  int e = blockIdx.x * blockDim.x + threadIdx.x;
  if (e < E) atomicAdd(&degi[dst[e]], 1);
}

// per-256 block sums of deg (also emits dinv — folds former k_dinv launch)
__global__ __launch_bounds__(256)
void k_part(const int* __restrict__ deg, int* __restrict__ part,
            float* __restrict__ dinv, int n) {
  __shared__ int l[256];
  int tid = threadIdx.x, i = blockIdx.x * 256 + tid;
  int v = (i < n) ? deg[i] : 0;
  if (i < n) dinv[i] = rsqrtf((float)(v + 1));  // +1 self-loop
  l[tid] = v;
  __syncthreads();
  for (int s = 128; s; s >>= 1) { if (tid < s) l[tid] += l[tid + s]; __syncthreads(); }
  if (!tid) part[blockIdx.x] = l[0];
}

__global__ __launch_bounds__(1024)
void k_scanpart(int* __restrict__ part, int np, int* __restrict__ off_n) {
  __shared__ int l[1024];
  int tid = threadIdx.x;
  int v = (tid < np) ? part[tid] : 0;
  l[tid] = v;
  __syncthreads();
  for (int s = 1; s < 1024; s <<= 1) {
    int t = (tid >= s) ? l[tid - s] : 0;
    __syncthreads();
    l[tid] += t;
    __syncthreads();
  }
  if (tid < np) part[tid] = l[tid] - v;   // exclusive
  if (tid == np - 1) *off_n = l[tid];     // total = E
}

// exclusive scan within block + partial base; also zero-inits cursor
__global__ __launch_bounds__(256)
void k_off(const int* __restrict__ deg, const int* __restrict__ part,
           int* __restrict__ off, int* __restrict__ cursor, int n) {
  __shared__ int l[256];
  int tid = threadIdx.x, i = blockIdx.x * 256 + tid;
  int v = (i < n) ? deg[i] : 0;
  l[tid] = v;
  __syncthreads();
  for (int s = 1; s < 256; s <<= 1) {
    int t = (tid >= s) ? l[tid - s] : 0;
    __syncthreads();
    l[tid] += t;
    __syncthreads();
  }
  if (i < n) {
    off[i] = part[blockIdx.x] + l[tid] - v;
    cursor[i] = 0;
  }
}

__global__ void k_scatter(const int* __restrict__ srcv, const int* __restrict__ dstv,
                          const float* __restrict__ dinv, const int* __restrict__ off,
                          int* __restrict__ cursor, int* __restrict__ csr_src,
                          float* __restrict__ csr_norm, int E) {
  int e = blockIdx.x * blockDim.x + threadIdx.x;
  if (e >= E) return;
  int d = dstv[e];
  int p = atomicAdd(&cursor[d], 1);
  int slot = off[d] + p;
  int s = srcv[e];
  csr_src[slot] = s;
  csr_norm[slot] = dinv[s] * dinv[d];
}

// ---------------- x (f32) -> bf16 ----------------

__global__ void k_cvtx(const float* __restrict__ x, unsigned short* __restrict__ xb,
                       long n4) {
  long t = (long)blockIdx.x * blockDim.x + threadIdx.x;
  if (t >= n4) return;
  float4 v = ((const float4*)x)[t];
  unsigned lo = (unsigned)f2b(v.x) | ((unsigned)f2b(v.y) << 16);
  unsigned hi = (unsigned)f2b(v.z) | ((unsigned)f2b(v.w) << 16);
  ((uint2*)xb)[t] = make_uint2(lo, hi);
}

// ---------------- weight convert: fp32 [128,128] -> fragment-packed bf16 ----------

__global__ __launch_bounds__(256)
void k_cvtw(const float* gw0, const float* gw1, const float* gw2,
            const float* wk, const float* wv, const float* wq, const float* ow,
            unsigned short* gwT0, unsigned short* gwT1, unsigned short* gwT2,
            unsigned short* wkvT, unsigned short* wqT, unsigned short* owT) {
  const float* src; unsigned short* dst;
  switch (blockIdx.y) {
    case 0: src = gw0; dst = gwT0; break;
    case 1: src = gw1; dst = gwT1; break;
    case 2: src = gw2; dst = gwT2; break;
    case 3: src = wk;  dst = wkvT; break;
    case 4: src = wv;  dst = wkvT + 128 * 128; break;   // colblk 8..15
    case 5: src = wq;  dst = wqT; break;
    default: src = ow; dst = owT; break;
  }
  int t = blockIdx.x * 256 + threadIdx.x;   // grid.x = 64
  int r = t >> 7, c = t & 127;              // r = k (input dim), c = out col
  dst[pk_off(c, r)] = f2b(src[t]);
}

// ---------------- fused GCN layer (R13/R17-proven anchor) ----------------
// out = LN(relu((A_hat @ prev) @ W + b)) + prev, using (A_hat H) W == A_hat (H W).
// Block = 128 thr (2 waves) = 16 nodes; wave aggregates 8 nodes, 4 rows per
// b128 gather instruction, 16 loads in flight. Measured-final form:
// cross-node pipelining is compiler-blocked (R12/R14/R16 spilled), occupancy
// lift null (R15), LDS idx staging negative (R18). Do not carry values across t.

__global__ __launch_bounds__(128, 6)
void k_gcn_layer(const unsigned short* __restrict__ embp,  // [N][128] bf16
                 const int* __restrict__ off, const int* __restrict__ csr_src,
                 const float* __restrict__ csr_norm, const float* __restrict__ dinv,
                 const unsigned short* __restrict__ wT,    // fragment-packed
                 const float* __restrict__ bias,
                 const float* __restrict__ ln_g, const float* __restrict__ ln_b,
                 unsigned short* __restrict__ embo, int N) {
  __shared__ unsigned a_sw[16 * 64];      // 16 rows x 256B, 16B-chunk XOR swizzle
  __shared__ float lnsum[16][2], lnsq[16][2];

  int tid = threadIdx.x, lane = tid & 63, w = tid >> 6;
  int g = lane >> 4, c16 = lane & 15;
  long n0 = (long)blockIdx.x * 16;

  // ---- phase A: aggregate 8 nodes for this wave
#pragma unroll
  for (int t = 0; t < 8; ++t) {
    int row = w * 8 + t;
    long node = n0 + row;
    long nc = node < N ? node : N - 1;
    float dn = dinv[nc];
    int s0 = off[nc], s1 = off[nc + 1];
    float acc[8];
    {
      uint4 rs_ = *(const uint4*)&embp[nc * 128 + c16 * 8];
      float wgt = (g == 0) ? dn * dn : 0.f;   // self loop counted once
      float2 f;
      f = upk(rs_.x); acc[0] = f.x * wgt; acc[1] = f.y * wgt;
      f = upk(rs_.y); acc[2] = f.x * wgt; acc[3] = f.y * wgt;
      f = upk(rs_.z); acc[4] = f.x * wgt; acc[5] = f.y * wgt;
      f = upk(rs_.w); acc[6] = f.x * wgt; acc[7] = f.y * wgt;
    }
    for (int i = s0; i < s1; i += 16) {
      int id[4]; float nm[4];
#pragma unroll
      for (int u = 0; u < 4; ++u) {
        int j = i + u * 4 + g;
        int jj = j < s1 ? j : s1 - 1;
        id[u] = csr_src[jj];
        nm[u] = j < s1 ? csr_norm[jj] : 0.f;
      }
      uint4 rv[4];
#pragma unroll
      for (int u = 0; u < 4; ++u)
        rv[u] = *(const uint4*)&embp[(long)id[u] * 128 + c16 * 8];
#pragma unroll
      for (int u = 0; u < 4; ++u) {
        float2 f0 = upk(rv[u].x), f1 = upk(rv[u].y);
        float2 f2 = upk(rv[u].z), f3 = upk(rv[u].w);
        acc[0] += f0.x * nm[u]; acc[1] += f0.y * nm[u];
        acc[2] += f1.x * nm[u]; acc[3] += f1.y * nm[u];
        acc[4] += f2.x * nm[u]; acc[5] += f2.y * nm[u];
        acc[6] += f3.x * nm[u]; acc[7] += f3.y * nm[u];
      }
    }
    // combine the 4 row-groups (lanes differing in bits 4,5)
#pragma unroll
    for (int k = 0; k < 8; ++k) {
      acc[k] += __shfl_xor(acc[k], 16);
      acc[k] += __shfl_xor(acc[k], 32);
    }
    if (g == 0) {
      unsigned* dst = (unsigned*)((char*)a_sw +
                      (row * 256 + ((c16 * 16) ^ ((row & 7) << 4))));
      dst[0] = (unsigned)f2b(acc[0]) | ((unsigned)f2b(acc[1]) << 16);
      dst[1] = (unsigned)f2b(acc[2]) | ((unsigned)f2b(acc[3]) << 16);
      dst[2] = (unsigned)f2b(acc[4]) | ((unsigned)f2b(acc[5]) << 16);
      dst[3] = (unsigned)f2b(acc[6]) | ((unsigned)f2b(acc[7]) << 16);
    }
  }
  __syncthreads();

  // ---- phase B: [16,128] = A @ W ; this wave: cols w*64..+64 (packed B loads)
  int lo = lane & 15, hi = lane >> 4;
  f32x4 acc2[4] = {};
#pragma unroll
  for (int ks = 0; ks < 4; ++ks) {
    int k0 = ks * 32 + hi * 8;
    bf16x8 a = *(const bf16x8*)((char*)a_sw + lo * 256 + ((k0 * 2) ^ ((lo & 7) << 4)));
#pragma unroll
    for (int cf = 0; cf < 4; ++cf) {
      bf16x8 b = *(const bf16x8*)&wT[((((long)(w * 4 + cf)) * 4 + ks) * 64 + lane) * 8];
      acc2[cf] = __builtin_amdgcn_mfma_f32_16x16x32_bf16(a, b, acc2[cf], 0, 0, 0);
    }
  }

  // ---- phase C: bias + relu + LN + residual + store
  int cb0 = w * 64;
  float vreg[4][4];   // [cf][j] ; row = hi*4+j, col = cb0+cf*16+lo
#pragma unroll
  for (int j = 0; j < 4; ++j) {
    float s = 0.f, q = 0.f;
#pragma unroll
    for (int cf = 0; cf < 4; ++cf) {
      int col = cb0 + cf * 16 + lo;
      float v = fmaxf(acc2[cf][j] + bias[col], 0.f);
      vreg[cf][j] = v;
      s += v; q += v * v;
    }
#pragma unroll
    for (int m = 1; m < 16; m <<= 1) { s += __shfl_xor(s, m); q += __shfl_xor(q, m); }
    if (lo == 0) { lnsum[hi * 4 + j][w] = s; lnsq[hi * 4 + j][w] = q; }
  }
  __syncthreads();
#pragma unroll
  for (int j = 0; j < 4; ++j) {
    int row = hi * 4 + j;
    float sum = lnsum[row][0] + lnsum[row][1];
    float sq  = lnsq[row][0] + lnsq[row][1];
    float mu = sum * (1.f / 128.f);
    float var = sq * (1.f / 128.f) - mu * mu;
    float rs = rsqrtf(var + 1e-5f);
    long gr = n0 + row;
    if (gr < N) {
#pragma unroll
      for (int cf = 0; cf < 4; ++cf) {
        int col = cb0 + cf * 16 + lo;
        float z = (vreg[cf][j] - mu) * rs * ln_g[col] + ln_b[col]
                  + b2f(embp[gr * 128 + col]);
        embo[gr * 128 + col] = f2b(z);
      }
    }
  }
}

// ---------------- fused: kv-proj + q-proj + attention + LN + out-proj ----------------
// R11-proven structure: fragment-packed B weights (1KB coalesced wave-loads).
// Block = 256 thr (4 waves) handles 16 nodes. emb layout [3][N][128] bf16.

__global__ __launch_bounds__(256)
void k_attn_fused(const unsigned short* __restrict__ emb,   // [3][N][128]
                  const unsigned short* __restrict__ wkvT,  // packed, colblk 0-7=K, 8-15=V
                  const unsigned short* __restrict__ wqT,   // packed
                  const unsigned short* __restrict__ owT,   // packed
                  const float* __restrict__ ln_g, const float* __restrict__ ln_b,
                  const float* __restrict__ out_b,
                  unsigned short* __restrict__ zoutb, int N) {
  __shared__ unsigned short kvl[48 * 256];  // row = l*16+node : [K 0..127 | V 128..255]
  __shared__ unsigned short ql[16 * 128];
  __shared__ unsigned short zl[16 * 128];   // XOR-swizzled (byte ^= (row&7)<<4)

  int tid = threadIdx.x, lane = tid & 63, w = tid >> 6;
  int lo = lane & 15, hi = lane >> 4;
  long n0 = (long)blockIdx.x * 16;
  long nr = n0 + lo; if (nr >= N) nr = N - 1;

  // ---- phase 1: KV[48,256] = emb-tile @ Wkv ; this wave: cols w*64..+64
  {
    f32x4 acc[3][4] = {};
#pragma unroll
    for (int ks = 0; ks < 4; ++ks) {
      int k0 = ks * 32 + hi * 8;
      bf16x8 a[3];
#pragma unroll
      for (int l = 0; l < 3; ++l)
        a[l] = *(const bf16x8*)&emb[((long)l * N + nr) * 128 + k0];
#pragma unroll
      for (int cf = 0; cf < 4; ++cf) {
        bf16x8 b = *(const bf16x8*)&wkvT[((((long)(w * 4 + cf)) * 4 + ks) * 64 + lane) * 8];
#pragma unroll
        for (int l = 0; l < 3; ++l)
          acc[l][cf] = __builtin_amdgcn_mfma_f32_16x16x32_bf16(a[l], b, acc[l][cf], 0, 0, 0);
      }
    }
    int cb0 = w * 64;
#pragma unroll
    for (int l = 0; l < 3; ++l)
#pragma unroll
      for (int cf = 0; cf < 4; ++cf)
#pragma unroll
        for (int j = 0; j < 4; ++j)
          kvl[(l * 16 + hi * 4 + j) * 256 + cb0 + cf * 16 + lo] = f2b(acc[l][cf][j]);
  }

  // ---- phase 2: Q[16,128] = layer2-tile @ Wq ; this wave: cols w*32..+32
  {
    f32x4 aq[2] = {};
#pragma unroll
    for (int ks = 0; ks < 4; ++ks) {
      int k0 = ks * 32 + hi * 8;
      bf16x8 a = *(const bf16x8*)&emb[(2L * N + nr) * 128 + k0];
#pragma unroll
      for (int cf = 0; cf < 2; ++cf) {
        bf16x8 b = *(const bf16x8*)&wqT[((((long)(w * 2 + cf)) * 4 + ks) * 64 + lane) * 8];
        aq[cf] = __builtin_amdgcn_mfma_f32_16x16x32_bf16(a, b, aq[cf], 0, 0, 0);
      }
    }
    int cq0 = w * 32;
#pragma unroll
    for (int cf = 0; cf < 2; ++cf)
#pragma unroll
      for (int j = 0; j < 4; ++j)
        ql[(hi * 4 + j) * 128 + cq0 + cf * 16 + lo] = f2b(aq[cf][j]);
  }
  __syncthreads();

  // ---- phase 3: attention + LN ; wave handles nodes w*4 .. w*4+3
  {
    const unsigned* kvu = (const unsigned*)kvl;
    const unsigned* qu  = (const unsigned*)ql;
    int c = lane * 2;
    float gx = ln_g[c], gy = ln_g[c + 1], bx = ln_b[c], by = ln_b[c + 1];
#pragma unroll
    for (int it = 0; it < 4; ++it) {
      int node = w * 4 + it;
      float2 q = upk(qu[node * 64 + lane]);
      float s[3], vx[3], vy[3];
#pragma unroll
      for (int m = 0; m < 3; ++m) {
        int row = m * 16 + node;
        float2 k = upk(kvu[row * 128 + lane]);
        float2 v = upk(kvu[row * 128 + 64 + lane]);
        float p = q.x * k.x + q.y * k.y;
        p += __shfl_xor(p, 1); p += __shfl_xor(p, 2); p += __shfl_xor(p, 4);
        s[m] = p * 0.25f;   // /sqrt(16)
        vx[m] = v.x; vy[m] = v.y;
      }
      float mx = fmaxf(s[0], fmaxf(s[1], s[2]));
      float e0 = __expf(s[0] - mx), e1 = __expf(s[1] - mx), e2 = __expf(s[2] - mx);
      float inv = 1.f / (e0 + e1 + e2);
      float cx = (e0 * vx[0] + e1 * vx[1] + e2 * vx[2]) * inv;
      float cy = (e0 * vy[0] + e1 * vy[1] + e2 * vy[2]) * inv;
      float sum = cx + cy, sq = cx * cx + cy * cy;
#pragma unroll
      for (int m = 1; m < 64; m <<= 1) { sum += __shfl_xor(sum, m); sq += __shfl_xor(sq, m); }
      float mu = sum * (1.f / 128.f);
      float var = sq * (1.f / 128.f) - mu * mu;
      float rs = rsqrtf(var + 1e-5f);
      unsigned pk = (unsigned)f2b((cx - mu) * rs * gx + bx) |
                    ((unsigned)f2b((cy - mu) * rs * gy + by) << 16);
      *(unsigned*)((char*)zl + node * 256 + ((lane * 4) ^ ((node & 7) << 4))) = pk;
    }
  }
  __syncthreads();

  // ---- phase 4: zout[16,128] = z @ Wo + out_b (bf16 store) ; cols w*32..+32
  {
    int co0 = w * 32;
    f32x4 ao[2] = {};
#pragma unroll
    for (int ks = 0; ks < 4; ++ks) {
      int k0 = ks * 32 + hi * 8;
      bf16x8 a = *(const bf16x8*)((const char*)zl + lo * 256 + (((k0 * 2) ^ ((lo & 7) << 4))));
#pragma unroll
      for (int cf = 0; cf < 2; ++cf) {
        bf16x8 b = *(const bf16x8*)&owT[((((long)(w * 2 + cf)) * 4 + ks) * 64 + lane) * 8];
        ao[cf] = __builtin_amdgcn_mfma_f32_16x16x32_bf16(a, b, ao[cf], 0, 0, 0);
      }
    }
#pragma unroll
    for (int cf = 0; cf < 2; ++cf)
#pragma unroll
      for (int j = 0; j < 4; ++j) {
        long gn = n0 + hi * 4 + j;
        int col = co0 + cf * 16 + lo;
        if (gn < N) zoutb[gn * 128 + col] = f2b(ao[cf][j] + out_b[col]);
      }
  }
}

// ---------------- gather rows (bf16 zout -> f32 out); blockIdx.y = id set --------

__global__ void k_gather4(const unsigned short* __restrict__ zoutb,
                          const int* __restrict__ ids0, const int* __restrict__ ids1,
                          const int* __restrict__ ids2, const int* __restrict__ ids3,
                          float* __restrict__ outp, int rows) {
  int t = blockIdx.x * blockDim.x + threadIdx.x;  // one 16B bf16 chunk per thread
  if (t >= rows * 16) return;
  int s = blockIdx.y;
  const int* ids = (s == 0) ? ids0 : (s == 1) ? ids1 : (s == 2) ? ids2 : ids3;
  int row = t >> 4, c8 = t & 15;
  long id = ids[row];
  uint4 v = *(const uint4*)&zoutb[id * 128 + c8 * 8];
  float2 f0 = upk(v.x), f1 = upk(v.y), f2_ = upk(v.z), f3 = upk(v.w);
  float4* dst = (float4*)&outp[(((long)s * rows + row) * 128) + c8 * 8];
  dst[0] = make_float4(f0.x, f0.y, f1.x, f1.y);
  dst[1] = make_float4(f2_.x, f2_.y, f3.x, f3.y);
}

// ---------------- host ----------------

extern "C" void kernel_launch(void* const* d_in, const int* in_sizes, int n_in,
                              void* d_out, int out_size, void* d_ws, size_t ws_size,
                              hipStream_t stream) {
  const float* x = (const float*)d_in[0];
  const int* ei = (const int*)d_in[1];
  const int* ids[4] = {(const int*)d_in[2], (const int*)d_in[3],
                       (const int*)d_in[4], (const int*)d_in[5]};
  const float* gw[3] = {(const float*)d_in[7], (const float*)d_in[9], (const float*)d_in[11]};
  const float* gb[3] = {(const float*)d_in[8], (const float*)d_in[10], (const float*)d_in[12]};
  const float* wq = (const float*)d_in[13];
  const float* wk = (const float*)d_in[14];
  const float* wv = (const float*)d_in[15];
  const float* ln_g = (const float*)d_in[16];
  const float* ln_b = (const float*)d_in[17];
  const float* out_w = (const float*)d_in[18];
  const float* out_b = (const float*)d_in[19];

  const int N = in_sizes[0] / 128;
  const int E = in_sizes[1] / 2;
  const int P = in_sizes[2];

  char* w = (char*)d_ws;
  size_t o = 0;
  auto take = [&](size_t bytes) -> void* {
    void* p = w + o;
    o = (o + bytes + 255) & ~(size_t)255;
    return p;
  };
  int*   degi    = (int*)take((size_t)N * 4);
  int*   off     = (int*)take((size_t)(N + 1) * 4);
  int*   cursor  = (int*)take((size_t)N * 4);
  int*   part    = (int*)take(1024 * 4);
  float* dinv    = (float*)take((size_t)N * 4);
  int*   csr_src = (int*)take((size_t)E * 4);
  float* csr_nrm = (float*)take((size_t)E * 4);
  unsigned short* gwT0 = (unsigned short*)take(128 * 128 * 2);
  unsigned short* gwT1 = (unsigned short*)take(128 * 128 * 2);
  unsigned short* gwT2 = (unsigned short*)take(128 * 128 * 2);
  unsigned short* wkvT = (unsigned short*)take(256 * 128 * 2);
  unsigned short* wqT  = (unsigned short*)take(128 * 128 * 2);
  unsigned short* owT  = (unsigned short*)take(128 * 128 * 2);
  unsigned short* xbf  = (unsigned short*)take((size_t)N * 128 * 2);
  unsigned short* emball = (unsigned short*)take((size_t)3 * N * 128 * 2);
  unsigned short* zoutb = (unsigned short*)take((size_t)N * 128 * 2);
  (void)ws_size; (void)n_in; (void)out_size;

  hipMemsetAsync(degi, 0, (size_t)N * 4, stream);

  int eb = (E + 255) / 256;
  int nb = (N + 255) / 256;
  k_degree<<<eb, 256, 0, stream>>>(ei + E, degi, E);
  k_part<<<nb, 256, 0, stream>>>(degi, part, dinv, N);
  k_scanpart<<<1, 1024, 0, stream>>>(part, nb, off + N);
  k_off<<<nb, 256, 0, stream>>>(degi, part, off, cursor, N);
  k_scatter<<<eb, 256, 0, stream>>>(ei, ei + E, dinv, off, cursor, csr_src, csr_nrm, E);
  k_cvtw<<<dim3(64, 7), 256, 0, stream>>>(gw[0], gw[1], gw[2], wk, wv, wq, out_w,
                                          gwT0, gwT1, gwT2, wkvT, wqT, owT);
  long n4 = (long)N * 32;
  k_cvtx<<<(int)((n4 + 255) / 256), 256, 0, stream>>>(x, xbf, n4);

  unsigned short* gwT[3] = {gwT0, gwT1, gwT2};
  int lgrid = (N + 15) / 16;
  const unsigned short* prev = xbf;
  for (int l = 0; l < 3; ++l) {
    unsigned short* outp = emball + (size_t)l * N * 128;
    k_gcn_layer<<<lgrid, 128, 0, stream>>>(prev, off, csr_src, csr_nrm, dinv,
                                           gwT[l], gb[l], ln_g, ln_b, outp, N);
    prev = outp;
  }

  // fused kv/q projections + attention + LN + out-proj (packed weights, bf16 zout)
  k_attn_fused<<<(N + 15) / 16, 256, 0, stream>>>(emball, wkvT, wqT, owT,
                                                  ln_g, ln_b, out_b, zoutb, N);

  float* outf = (float*)d_out;
  int gb2 = (P * 16 + 255) / 256;
  k_gather4<<<dim3(gb2, 4), 256, 0, stream>>>(zoutb, ids[0], ids[1], ids[2], ids[3],
                                              outf, P);
}